// Round 11
// baseline (252.286 us; speedup 1.0000x reference)
//
#include <hip/hip_runtime.h>
#include <math.h>

// Real grid (match reference): 421 x 421 E-grid, source at (210,210)
#define NXr 421
#define CXr 210
#define NSTEPS_C 200

// Round 22 = champion packed 2x2 body (R19, 245.1 us) at R15's PHASE COUNT:
// Bt=32, Kt=16, EXT=64 -> redundancy stays 4x, but 1024 threads x 2x2 cells
// (R15's failure was the 4x4 body at 4 waves/CU; here 16 waves/block ->
// ~16 waves/CU at the late 196-block grids, better than champion's 11.4).
// Dispatches 23 -> 13 (init + seed + 11 phases of 16 steps; last = 8).
// Model (R19/R21 calibration): per-step ~0.55us regardless of shape;
// total ~= 200*0.55 + N_disp*(gap 2.5 + fixed 2) -> cut N_disp at constant
// redundancy and high waves/CU. Seed (1024-thr, 0.55us/step) already proved
// this exact block shape + body at harness accuracy.
#define Bt   32
#define Kt   16
#define EXT  64                    // 32x32 threads x 2x2 cells
#define TDIM 32
#define NTHR (TDIM * TDIM)         // 1024 = 16 waves
#define LROWS (EXT + 2)            // 66
#define SPITCH 68                  // 2+64+2, even -> float2-aligned interior
#define RING_N (2 * SPITCH + (LROWS - 2) * 4)   // 392
#define NBLK 14                    // 14*32 = 448 >= 437 (real end in padded)

// Padded zero-ring layout: fields are PP x PP with the real 421^2 domain at
// offset (PAD,PAD), PAD = Kt. Coefficient tables are zero outside the real
// domain -> cells outside provably stay 0 forever -> all hot loads/stores
// unconditional float2 (u = cb*0+ce*0 = 0 preserved). A zeroed guard row
// (PP floats) in front of the field block makes row -1 ghost loads safe.
// Max tile extent: 13*32 + 64 = 480 = PP exactly.
#define PP   480
#define PAD  16
#define CP   (CXr + PAD)           // 226
#define FSZ  (PP * PP)

// Seed tile: 64x64 cells at [SB, SB+64) = [CP-32, CP+32)
#define SB   (CP - 32)             // 194
#define SEED_STEPS 32              // support radius <= 31 stays inside tile

typedef float v2f __attribute__((ext_vector_type(2)));
static __device__ __forceinline__ v2f mk2(float x, float y)
{ v2f r; r.x = x; r.y = y; return r; }

struct PParams {
    float *aEz, *aJz, *aU, *aHx, *aHy;          // state set A (5 fields)
    float *bEz, *bJz, *bU, *bHx, *bHy;          // state set B
    const float *dexP, *deyP, *aexP, *aeyP, *ahxP, *ahyP;  // padded 1-D tables
    const float *C1a, *C2a, *Cbdxa, *Cbdya;
    const float *Caa, *Cba, *Cca, *Cda, *Cea, *dbhxa, *dbhya;
    const float *src;
};

// ---------------------------------------------------------------------------
// Init: zero guard row + both padded state sets; build padded coeff tables.
// dexP/deyP fold the interior mask (nonzero only for real coords 1..419).
// Zeroing BOTH sets every call keeps the support-gating skip exact.
// ---------------------------------------------------------------------------
__global__ void init_kernel(const float* __restrict__ sig_ex,
                            const float* __restrict__ sig_ey,
                            const float* __restrict__ sig_hx,
                            const float* __restrict__ sig_hy,
                            float de_fac, float dh_fac,
                            float* __restrict__ zero_base, int n_zero,
                            float* __restrict__ dexP, float* __restrict__ deyP,
                            float* __restrict__ aexP, float* __restrict__ aeyP,
                            float* __restrict__ ahxP, float* __restrict__ ahyP)
{
    int t = blockIdx.x * blockDim.x + threadIdx.x;
    int stride = gridDim.x * blockDim.x;
    for (int k = t; k < n_zero; k += stride) zero_base[k] = 0.0f;
    if (t < PP) {
        int g = t - PAD;
        dexP[t] = (g >= 1 && g <= NXr - 2) ? expf(-sig_ex[g] * de_fac) : 0.0f;
        deyP[t] = (g >= 1 && g <= NXr - 2) ? expf(-sig_ey[g] * de_fac) : 0.0f;
        aexP[t] = (g >= 0 && g <  NXr)     ? expf(-sig_ex[g] * dh_fac) : 0.0f;
        aeyP[t] = (g >= 0 && g <  NXr)     ? expf(-sig_ey[g] * dh_fac) : 0.0f;
        ahxP[t] = (g >= 0 && g <  NXr - 1) ? expf(-sig_hx[g] * dh_fac) : 0.0f;
        ahyP[t] = (g >= 0 && g <  NXr - 1) ? expf(-sig_hy[g] * dh_fac) : 0.0f;
    }
}

// ---------------------------------------------------------------------------
// Seed: steps 0..31, one 1024-thread block, 64x64 tile, zero-start (no
// loads, no redundancy; ring reads = true zeros, support radius <= 31).
// Writes step-32 state for the FULL tile to set A. (Verified R19/R21.)
// ---------------------------------------------------------------------------
__global__ __launch_bounds__(NTHR)
void seed_kernel(PParams p)
{
    __shared__ __align__(16) float sE[2][LROWS][SPITCH];

    const int tid = threadIdx.x;
    const int tj = tid & 31, ti = tid >> 5;
    const int li0 = 2 * ti, lj0 = 2 * tj;
    const int r0 = SB + li0, c0 = SB + lj0;

    const float ca = p.Caa[0], cb = p.Cba[0], cc = p.Cca[0];
    const float cd = p.Cda[0], ce = p.Cea[0];
    const float ca1f = ca + 1.0f;
    const float C1f = p.C1a[0], C2f = p.C2a[0];
    const float cbdxf = p.Cbdxa[0], cbdyf = p.Cbdya[0];
    const float dbhx0 = p.dbhxa[0], dbhy0 = p.dbhya[0];

    const v2f vca1 = mk2(ca1f, ca1f), vcb = mk2(cb, cb), vcc = mk2(cc, cc);
    const v2f vcd = mk2(cd, cd), vce = mk2(ce, ce);
    const v2f vC1 = mk2(C1f, C1f), vC2 = mk2(C2f, C2f);
    const v2f vbx = mk2(cbdxf, cbdxf), vby = mk2(cbdyf, cbdyf);
    const v2f vhx = mk2(dbhx0, dbhx0), vhy = mk2(dbhy0, dbhy0);

    v2f dHx[2], dHy[2], dE[2], dHyU, srcw[2];
    float dHxL[2];
#pragma unroll
    for (int a = 0; a < 2; ++a) {
        float aex = p.aexP[r0 + a], ahxv = p.ahxP[r0 + a], dex = p.dexP[r0 + a];
        dHx[a] = mk2(aex * p.ahyP[c0], aex * p.ahyP[c0 + 1]);
        dHy[a] = mk2(ahxv * p.aeyP[c0], ahxv * p.aeyP[c0 + 1]);
        dE[a]  = mk2(dex * p.deyP[c0], dex * p.deyP[c0 + 1]);
        srcw[a] = mk2(((r0 + a == CP) && (c0 == CP)) ? 1.0f : 0.0f,
                      ((r0 + a == CP) && (c0 + 1 == CP)) ? 1.0f : 0.0f);
    }
    {
        float ahxU = p.ahxP[r0 - 1];          // r0-1 >= SB-1 = 193 >= 0
        float ahyL = p.ahyP[c0 - 1];
        dHyU = mk2(ahxU * p.aeyP[c0], ahxU * p.aeyP[c0 + 1]);
        dHxL[0] = p.aexP[r0] * ahyL;
        dHxL[1] = p.aexP[r0 + 1] * ahyL;
    }

    v2f ez[2] = {}, jz[2] = {}, uu[2] = {}, hx[2] = {}, hy[2] = {};
    v2f hyU = {};
    float hxL[2] = {};

    // Ring-only zero (publishes never touch the ring); the step-0 in-loop
    // barrier orders these writes vs all readers.
    for (int z = tid; z < 2 * RING_N; z += NTHR) {
        int b = (z >= RING_N) ? 1 : 0;
        int r = b ? z - RING_N : z;
        int row, col;
        if (r < 2 * SPITCH) { row = (r < SPITCH) ? 0 : (LROWS - 1); col = r % SPITCH; }
        else { int rr = r - 2 * SPITCH; row = 1 + (rr >> 2); int c = rr & 3;
               col = (c < 2) ? c : c + EXT; }
        sE[b][row][col] = 0.0f;
    }

    float svl[SEED_STEPS];
#pragma unroll
    for (int s = 0; s < SEED_STEPS; ++s) svl[s] = p.src[s];

#pragma unroll
    for (int s = 0; s < SEED_STEPS; ++s) {
        float (*S)[SPITCH] = sE[s & 1];
        *(float2*)&S[1 + li0][2 + lj0] = make_float2(ez[0].x, ez[0].y);
        *(float2*)&S[2 + li0][2 + lj0] = make_float2(ez[1].x, ez[1].y);

        hy[0] = dHy[0] * (hy[0] + vhy * (ez[1] - ez[0]));
        v2f w0 = hx[0] + vhx * ez[0];
        v2f w1 = hx[1] + vhx * ez[1];

        v2f phi0 = vca1 * jz[0] + vcd * ez[0] + uu[0];
        v2f phi1 = vca1 * jz[1] + vcd * ez[1] + uu[1];
        v2f base0 = vC1 * ez[0] - vC2 * phi0;
        v2f base1 = vC1 * ez[1] - vC2 * phi1;
        v2f pj0 = phi0 - jz[0];
        v2f pj1 = phi1 - jz[1];
        uu[0] = vcb * jz[0] + vce * ez[0];
        uu[1] = vcb * jz[1] + vce * ez[1];

        __syncthreads();

        float eR0 = S[1 + li0][4 + lj0];
        float eR1 = S[2 + li0][4 + lj0];
        float2 eDf = *(float2*)&S[3 + li0][2 + lj0];
        float2 eUf = *(float2*)&S[li0][2 + lj0];
        float eL0 = S[1 + li0][1 + lj0];
        float eL1 = S[2 + li0][1 + lj0];
        v2f eD = mk2(eDf.x, eDf.y), eU = mk2(eUf.x, eUf.y);

        v2f sh0 = mk2(ez[0].y, eR0);
        v2f sh1 = mk2(ez[1].y, eR1);
        hx[0] = dHx[0] * (w0 - vhx * sh0);
        hx[1] = dHx[1] * (w1 - vhx * sh1);
        hy[1] = dHy[1] * (hy[1] + vhy * (eD - ez[1]));

        hyU = dHyU * (hyU + vhy * (ez[0] - eU));
        hxL[0] = dHxL[0] * (hxL[0] - dbhx0 * (ez[0].x - eL0));
        hxL[1] = dHxL[1] * (hxL[1] - dbhx0 * (ez[1].x - eL1));

        v2f cHy0 = hy[0] - hyU;
        v2f cHy1 = hy[1] - hy[0];
        v2f cHx0 = hx[0] - mk2(hxL[0], hx[0].x);
        v2f cHx1 = hx[1] - mk2(hxL[1], hx[1].x);

        float sv = svl[s];
        v2f vsv = mk2(sv, sv);
        v2f en0 = dE[0] * (base0 + vbx * cHy0 - vby * cHx0) + srcw[0] * vsv;
        v2f en1 = dE[1] * (base1 + vbx * cHy1 - vby * cHx1) + srcw[1] * vsv;
        jz[0] = pj0 + vcc * en0;
        jz[1] = pj1 + vcc * en1;
        ez[0] = en0;
        ez[1] = en1;
    }

#pragma unroll
    for (int a = 0; a < 2; ++a) {
        int g = (r0 + a) * PP + c0;
        *(float2*)&p.aEz[g] = make_float2(ez[a].x, ez[a].y);
        *(float2*)&p.aJz[g] = make_float2(jz[a].x, jz[a].y);
        *(float2*)&p.aU[g]  = make_float2(uu[a].x, uu[a].y);
        *(float2*)&p.aHx[g] = make_float2(hx[a].x, hx[a].y);
        *(float2*)&p.aHy[g] = make_float2(hy[a].x, hy[a].y);
    }
}

// ---------------------------------------------------------------------------
// One temporal-blocked phase (SN steps, template-constant so the src array
// and step loop stay fully unrolled -> no scratch). 32x32 threads x 2x2
// cells = 64x64 tile, owned central 32x32 (tile coords [16,48) -> ti,tj in
// [8,24)). Ez-only LDS exchange, parity-double-buffered, ONE barrier/step.
// Ring-only zero, no pre-loop barrier. rw=0: read A write B; rw=1: reverse.
// writeOut: last phase emits the dense 421x421 output from registers.
// ---------------------------------------------------------------------------
template<int SN>
__global__ __launch_bounds__(NTHR)
void phase_kernel(PParams p, int n0, int b0, float* __restrict__ out,
                  int writeOut, int rw)
{
    __shared__ __align__(16) float sEz[2][LROWS][SPITCH];

    const int tid = threadIdx.x;
    const int tj = tid & 31, ti = tid >> 5;
    const int li0 = 2 * ti, lj0 = 2 * tj;

    // Bijective XCD-chunked swizzle (grid is always square). Pure permutation.
    const int gx = (int)gridDim.x;
    int orig = (int)blockIdx.y * gx + (int)blockIdx.x;
    int nwg = gx * gx;
    int q = nwg >> 3, rr = nwg & 7;
    int xcd = orig & 7, kk = orig >> 3;
    int nid = (xcd < rr ? xcd * (q + 1) : rr * (q + 1) + (xcd - rr) * q) + kk;
    int bx = nid % gx, by = nid / gx;

    const int r0 = (bx + b0) * Bt + li0;  // padded row, cell(0,*)
    const int c0 = (by + b0) * Bt + lj0;  // padded col, cell(*,0)

    const float ca = p.Caa[0], cb = p.Cba[0], cc = p.Cca[0];
    const float cd = p.Cda[0], ce = p.Cea[0];
    const float ca1f = ca + 1.0f;
    const float C1f = p.C1a[0], C2f = p.C2a[0];
    const float cbdxf = p.Cbdxa[0], cbdyf = p.Cbdya[0];
    const float dbhx0 = p.dbhxa[0], dbhy0 = p.dbhya[0];

    const v2f vca1 = mk2(ca1f, ca1f), vcb = mk2(cb, cb), vcc = mk2(cc, cc);
    const v2f vcd = mk2(cd, cd), vce = mk2(ce, ce);
    const v2f vC1 = mk2(C1f, C1f), vC2 = mk2(C2f, C2f);
    const v2f vbx = mk2(cbdxf, cbdxf), vby = mk2(cbdyf, cbdyf);
    const v2f vhx = mk2(dbhx0, dbhx0), vhy = mk2(dbhy0, dbhy0);

    v2f dHx[2], dHy[2], dE[2], dHyU, srcw[2];
    float dHxL[2];
#pragma unroll
    for (int a = 0; a < 2; ++a) {
        float aex = p.aexP[r0 + a], ahxv = p.ahxP[r0 + a], dex = p.dexP[r0 + a];
        dHx[a] = mk2(aex * p.ahyP[c0], aex * p.ahyP[c0 + 1]);
        dHy[a] = mk2(ahxv * p.aeyP[c0], ahxv * p.aeyP[c0 + 1]);
        dE[a]  = mk2(dex * p.deyP[c0], dex * p.deyP[c0 + 1]);
        srcw[a] = mk2(((r0 + a == CP) && (c0 == CP)) ? 1.0f : 0.0f,
                      ((r0 + a == CP) && (c0 + 1 == CP)) ? 1.0f : 0.0f);
    }
    {
        float ahxU = (r0 > 0) ? p.ahxP[r0 - 1] : 0.0f;   // table idx guard
        float ahyL = (c0 > 0) ? p.ahyP[c0 - 1] : 0.0f;
        dHyU = mk2(ahxU * p.aeyP[c0], ahxU * p.aeyP[c0 + 1]);
        dHxL[0] = p.aexP[r0] * ahyL;
        dHxL[1] = p.aexP[r0 + 1] * ahyL;
    }

    const float* cEz = rw ? p.bEz : p.aEz;
    const float* cJz = rw ? p.bJz : p.aJz;
    const float* cU  = rw ? p.bU  : p.aU;
    const float* cHx = rw ? p.bHx : p.aHx;
    const float* cHy = rw ? p.bHy : p.aHy;
    float* nEz = rw ? p.aEz : p.bEz;
    float* nJz = rw ? p.aJz : p.bJz;
    float* nU  = rw ? p.aU  : p.bU;
    float* nHx = rw ? p.aHx : p.bHx;
    float* nHy = rw ? p.aHy : p.bHy;

    // Ring-only zero (publishes never touch the ring); the step-0 in-loop
    // barrier orders these writes vs all readers.
    for (int z = tid; z < 2 * RING_N; z += NTHR) {
        int b = (z >= RING_N) ? 1 : 0;
        int r = b ? z - RING_N : z;
        int row, col;
        if (r < 2 * SPITCH) { row = (r < SPITCH) ? 0 : (LROWS - 1); col = r % SPITCH; }
        else { int rr2 = r - 2 * SPITCH; row = 1 + (rr2 >> 2); int c = rr2 & 3;
               col = (c < 2) ? c : c + EXT; }
        sEz[b][row][col] = 0.0f;
    }

    // Load 2x2 register state (unconditional padded float2) as packed rows
    v2f ez[2], jz[2], uu[2], hx[2], hy[2];
#pragma unroll
    for (int a = 0; a < 2; ++a) {
        int g = (r0 + a) * PP + c0;
        float2 v;
        v = *(const float2*)&cEz[g]; ez[a] = mk2(v.x, v.y);
        v = *(const float2*)&cJz[g]; jz[a] = mk2(v.x, v.y);
        v = *(const float2*)&cU[g];  uu[a] = mk2(v.x, v.y);
        v = *(const float2*)&cHx[g]; hx[a] = mk2(v.x, v.y);
        v = *(const float2*)&cHy[g]; hy[a] = mk2(v.x, v.y);
    }
    // Ghost H (row above / col left); guard row + zero pads make -1 safe
    v2f hyU;
    float hxL[2];
    {
        float2 v = *(const float2*)&cHy[(r0 - 1) * PP + c0];
        hyU = mk2(v.x, v.y);
        hxL[0] = cHx[r0 * PP + c0 - 1];
        hxL[1] = cHx[(r0 + 1) * PP + c0 - 1];
    }

    // Phase's SN source values (wave-uniform -> SGPR scalar loads)
    float svl[SN];
#pragma unroll
    for (int s = 0; s < SN; ++s) svl[s] = p.src[n0 + s];

#pragma unroll
    for (int s = 0; s < SN; ++s) {
        float (*S)[SPITCH] = sEz[s & 1];
        // publish all 4 Ez cells into the ring-padded interior
        *(float2*)&S[1 + li0][2 + lj0] = make_float2(ez[0].x, ez[0].y);
        *(float2*)&S[2 + li0][2 + lj0] = make_float2(ez[1].x, ez[1].y);

        // ---- pre-barrier (no neighbor deps) ----
        hy[0] = dHy[0] * (hy[0] + vhy * (ez[1] - ez[0]));
        v2f w0 = hx[0] + vhx * ez[0];
        v2f w1 = hx[1] + vhx * ez[1];

        v2f phi0 = vca1 * jz[0] + vcd * ez[0] + uu[0];
        v2f phi1 = vca1 * jz[1] + vcd * ez[1] + uu[1];
        v2f base0 = vC1 * ez[0] - vC2 * phi0;
        v2f base1 = vC1 * ez[1] - vC2 * phi1;
        v2f pj0 = phi0 - jz[0];
        v2f pj1 = phi1 - jz[1];
        uu[0] = vcb * jz[0] + vce * ez[0];
        uu[1] = vcb * jz[1] + vce * ez[1];

        __syncthreads();

        // Unconditional neighbor reads; tile-edge reads hit the zero ring.
        float eR0 = S[1 + li0][4 + lj0];
        float eR1 = S[2 + li0][4 + lj0];
        float2 eDf = *(float2*)&S[3 + li0][2 + lj0];
        float2 eUf = *(float2*)&S[li0][2 + lj0];
        float eL0 = S[1 + li0][1 + lj0];
        float eL1 = S[2 + li0][1 + lj0];
        v2f eD = mk2(eDf.x, eDf.y), eU = mk2(eUf.x, eUf.y);

        v2f sh0 = mk2(ez[0].y, eR0);
        v2f sh1 = mk2(ez[1].y, eR1);
        hx[0] = dHx[0] * (w0 - vhx * sh0);
        hx[1] = dHx[1] * (w1 - vhx * sh1);
        hy[1] = dHy[1] * (hy[1] + vhy * (eD - ez[1]));

        hyU = dHyU * (hyU + vhy * (ez[0] - eU));
        hxL[0] = dHxL[0] * (hxL[0] - dbhx0 * (ez[0].x - eL0));
        hxL[1] = dHxL[1] * (hxL[1] - dbhx0 * (ez[1].x - eL1));

        v2f cHy0 = hy[0] - hyU;
        v2f cHy1 = hy[1] - hy[0];
        v2f cHx0 = hx[0] - mk2(hxL[0], hx[0].x);
        v2f cHx1 = hx[1] - mk2(hxL[1], hx[1].x);

        float sv = svl[s];
        v2f vsv = mk2(sv, sv);
        v2f en0 = dE[0] * (base0 + vbx * cHy0 - vby * cHx0) + srcw[0] * vsv;
        v2f en1 = dE[1] * (base1 + vbx * cHy1 - vby * cHx1) + srcw[1] * vsv;
        jz[0] = pj0 + vcc * en0;
        jz[1] = pj1 + vcc * en1;
        ez[0] = en0;
        ez[1] = en1;
        // Single barrier per step: next iteration stores to the OTHER LDS
        // buffer (parity), so late readers of this buffer are safe.
    }

    // store owned interior [Kt, Kt+Bt)^2 = tile [16,48) -> ti,tj in [8,24)
    if (ti >= 8 && ti < 24 && tj >= 8 && tj < 24) {
#pragma unroll
        for (int a = 0; a < 2; ++a) {
            int g = (r0 + a) * PP + c0;
            *(float2*)&nEz[g] = make_float2(ez[a].x, ez[a].y);
            *(float2*)&nJz[g] = make_float2(jz[a].x, jz[a].y);
            *(float2*)&nU[g]  = make_float2(uu[a].x, uu[a].y);
            *(float2*)&nHx[g] = make_float2(hx[a].x, hx[a].y);
            *(float2*)&nHy[g] = make_float2(hy[a].x, hy[a].y);
        }
        // Last phase: owned regions tile the padded domain exactly; emit the
        // dense 421x421 output directly (same register values copy_out read).
        if (writeOut) {
#pragma unroll
            for (int a = 0; a < 2; ++a) {
                int gi = r0 + a - PAD;
                if (gi < NXr) {
                    int gj = c0 - PAD;
                    if (gj < NXr)     out[gi * NXr + gj]     = ez[a].x;
                    if (gj + 1 < NXr) out[gi * NXr + gj + 1] = ez[a].y;
                }
            }
        }
    }
}

// ---------------------------------------------------------------------------
extern "C" void kernel_launch(void* const* d_in, const int* in_sizes, int n_in,
                              void* d_out, int out_size, void* d_ws, size_t ws_size,
                              hipStream_t stream)
{
    const float* src    = (const float*)d_in[0];
    const float* C1     = (const float*)d_in[1];
    const float* C2     = (const float*)d_in[2];
    const float* Cb_dx  = (const float*)d_in[3];
    const float* Cb_dy  = (const float*)d_in[4];
    const float* dbhx   = (const float*)d_in[5];
    const float* dbhy   = (const float*)d_in[6];
    const float* Ca     = (const float*)d_in[7];
    const float* Cb     = (const float*)d_in[8];
    const float* Cc     = (const float*)d_in[9];
    const float* Cd     = (const float*)d_in[10];
    const float* Ce     = (const float*)d_in[11];
    const float* sig_ex = (const float*)d_in[12];
    const float* sig_ey = (const float*)d_in[13];
    const float* sig_hx = (const float*)d_in[14];
    const float* sig_hy = (const float*)d_in[15];
    // d_in[16] = n_steps (always 200) — hard-coded for graph capture.

    const double EPS0 = 1e-9 / 36.0 / M_PI;
    const double MU0  = 4.0 * M_PI * 1e-7;
    const double C0   = 1.0 / sqrt(MU0 * EPS0);
    const double DXd  = 2.5e-8, DYd = 2.5e-8;
    const double DT   = 0.99 / C0 / sqrt(1.0 / (DXd * DXd) + 1.0 / (DYd * DYd));
    const float de_fac = (float)(DT / EPS0);
    const float dh_fac = (float)(DT / MU0);

    // Workspace: [guard row PP][10 padded fields][6 padded tables] (~9.2 MB)
    float* base = (float*)d_ws;
    float* fields = base + PP;
    float* w = fields + 10 * (size_t)FSZ;
    float* dexP = w; w += PP;
    float* deyP = w; w += PP;
    float* aexP = w; w += PP;
    float* aeyP = w; w += PP;
    float* ahxP = w; w += PP;
    float* ahyP = w; w += PP;

    PParams p;
    p.aEz = fields + 0 * (size_t)FSZ;  p.aJz = fields + 1 * (size_t)FSZ;
    p.aU  = fields + 2 * (size_t)FSZ;  p.aHx = fields + 3 * (size_t)FSZ;
    p.aHy = fields + 4 * (size_t)FSZ;
    p.bEz = fields + 5 * (size_t)FSZ;  p.bJz = fields + 6 * (size_t)FSZ;
    p.bU  = fields + 7 * (size_t)FSZ;  p.bHx = fields + 8 * (size_t)FSZ;
    p.bHy = fields + 9 * (size_t)FSZ;
    p.dexP = dexP; p.deyP = deyP; p.aexP = aexP; p.aeyP = aeyP;
    p.ahxP = ahxP; p.ahyP = ahyP;
    p.C1a = C1; p.C2a = C2; p.Cbdxa = Cb_dx; p.Cbdya = Cb_dy;
    p.Caa = Ca; p.Cba = Cb; p.Cca = Cc; p.Cda = Cd; p.Cea = Ce;
    p.dbhxa = dbhx; p.dbhya = dbhy;
    p.src = src;

    init_kernel<<<512, 256, 0, stream>>>(sig_ex, sig_ey, sig_hx, sig_hy,
                                         de_fac, dh_fac,
                                         base, PP + 10 * FSZ,
                                         dexP, deyP, aexP, aeyP, ahxP, ahyP);

    // Steps 0..31 in one zero-redundancy 1024-thread dispatch. Writes set A.
    seed_kernel<<<1, NTHR, 0, stream>>>(p);

    // Phases i=0..10: steps 32+16i..; i=10 runs 8 steps (halo 16 >= 8).
    // Parity is dispatch-indexed: i even reads A writes B; i odd reverse.
    // Support bound: end of phase i is step 48+16i -> radius 47+16i.
    // Gate R = 16i+51 (radius+4; tile-extent test adds more slack). Launch
    // sets monotone in i -> ping-pong zero-invariant holds (audited: phase
    // i's support is inside phase (i-2)'s owned union). i=10: R=211 -> full
    // 14x14 grid, every owned cell written to out. Capture-safe (i-only).
    for (int i = 0; i <= 10; ++i) {
        int R  = 16 * i + 51;
        int lo = CP - R, hi = CP + R;
        int b0 = (lo - (EXT - 1)) / Bt; if (b0 < 0) b0 = 0;
        int b1 = hi / Bt;               if (b1 > NBLK - 1) b1 = NBLK - 1;
        dim3 g(b1 - b0 + 1, b1 - b0 + 1);
        int n0 = 32 + 16 * i;
        if (i == 10)
            phase_kernel<8><<<g, dim3(NTHR), 0, stream>>>(
                p, n0, b0, (float*)d_out, 1, i & 1);
        else
            phase_kernel<16><<<g, dim3(NTHR), 0, stream>>>(
                p, n0, b0, (float*)d_out, 0, i & 1);
    }
    // No copy_out dispatch: phase i=10 wrote the dense output directly.
}

// Round 12
// 247.076 us; speedup vs baseline: 1.0211x; 1.0211x over previous
//
#include <hip/hip_runtime.h>
#include <math.h>

// Real grid (match reference): 421 x 421 E-grid, source at (210,210)
#define NXr 421
#define CXr 210
#define NSTEPS_C 200

// Round 23 = REVERT to R19 champion (245.1 us: seed + ring-zero + packed
// 5-field body, Kt=8/Bt=16/EXT=32, 23 dispatches) + two safe micro-cuts:
//  1) gate R = 8t+11 -> 8t+9. Skip-safety: a tile NOT launched at phase t
//     has extent disjoint from B(8t+9) => its owned region is disjoint from
//     B(8t+7) = support at end of phase t => true field there is 0 = its
//     stale init-zero. Launch sets stay monotone in t (R increasing), so the
//     ping-pong zero-invariant is unchanged.
//  2) block-uniform source gating: the srcw FMA pair issues only in the one
//     block whose 32x32 extent contains (CP,CP) (uniform SCC branch).
// Session model (R13-R22 bracketing): total ~= 23 x 4.5us dispatch overhead
// (persistent sync measured 2.5x worse -> boundaries are the cheap sync)
// + 200 x ~0.55us chain latency (90% of step time; fusion to halve chains is
// provably LDS-bw-bound). This structure is the measured local optimum.
#define Bt   16
#define Kt   8
#define EXT  32
#define LROWS (EXT + 2)            // 34: zero ring row above/below
#define SPITCH 36                  // 2+32+2 cols, even => float2-aligned interior
#define RING_N (2 * SPITCH + (LROWS - 2) * 4)   // ring cells per buffer
#define NBLK 27                    // 27*16 = 432 computational domain
#define NPHASE (NSTEPS_C / Kt)     // 25 step-phases; 0..3 done by seed

// Padded zero-ring layout: fields are PP x PP with the computational domain
// [0,432)^2 at offset (PAD,PAD). Coefficient tables are zero outside the real
// 421^2 domain, so cells outside it provably stay 0 forever -> all hot
// loads/stores are unconditional float2 (u = cb*0+ce*0 = 0 preserved). A
// zeroed guard row (PP floats) sits in front of the field block so ghost
// loads at padded row/col -1 are safe.
#define PP   448
#define PAD  8
#define CP   (CXr + PAD)           // source in padded coords: 218
#define FSZ  (PP * PP)             // floats per padded field

// Seed tile: 64x64 cells at rows/cols [SB, SB+64) = [CP-32, CP+32)
#define SB   (CP - 32)             // 186
#define SEED_STEPS 32              // support radius <= 31 stays inside tile
#define SROWS 66                   // 1 + 64 + 1 ring rows
#define SPITCH2 68                 // 2+64+2 cols
#define RING_N2 (2 * SPITCH2 + (SROWS - 2) * 4) // ring cells per buffer

typedef float v2f __attribute__((ext_vector_type(2)));
static __device__ __forceinline__ v2f mk2(float x, float y)
{ v2f r; r.x = x; r.y = y; return r; }

struct PParams {
    float *aEz, *aJz, *aU, *aHx, *aHy;          // state set A (5 fields)
    float *bEz, *bJz, *bU, *bHx, *bHy;          // state set B
    const float *dexP, *deyP, *aexP, *aeyP, *ahxP, *ahyP;  // padded 1-D tables
    const float *C1a, *C2a, *Cbdxa, *Cbdya;
    const float *Caa, *Cba, *Cca, *Cda, *Cea, *dbhxa, *dbhya;
    const float *src;
};

// ---------------------------------------------------------------------------
// Init: zero guard row + both padded state sets; build padded coeff tables.
// dexP/deyP fold the interior mask (nonzero only for real coords 1..419).
// Zeroing BOTH sets every call keeps the support-gating skip exact.
// ---------------------------------------------------------------------------
__global__ void init_kernel(const float* __restrict__ sig_ex,
                            const float* __restrict__ sig_ey,
                            const float* __restrict__ sig_hx,
                            const float* __restrict__ sig_hy,
                            float de_fac, float dh_fac,
                            float* __restrict__ zero_base, int n_zero,
                            float* __restrict__ dexP, float* __restrict__ deyP,
                            float* __restrict__ aexP, float* __restrict__ aeyP,
                            float* __restrict__ ahxP, float* __restrict__ ahyP)
{
    int t = blockIdx.x * blockDim.x + threadIdx.x;
    int stride = gridDim.x * blockDim.x;
    for (int k = t; k < n_zero; k += stride) zero_base[k] = 0.0f;
    if (t < PP) {
        int g = t - PAD;
        dexP[t] = (g >= 1 && g <= NXr - 2) ? expf(-sig_ex[g] * de_fac) : 0.0f;
        deyP[t] = (g >= 1 && g <= NXr - 2) ? expf(-sig_ey[g] * de_fac) : 0.0f;
        aexP[t] = (g >= 0 && g <  NXr)     ? expf(-sig_ex[g] * dh_fac) : 0.0f;
        aeyP[t] = (g >= 0 && g <  NXr)     ? expf(-sig_ey[g] * dh_fac) : 0.0f;
        ahxP[t] = (g >= 0 && g <  NXr - 1) ? expf(-sig_hx[g] * dh_fac) : 0.0f;
        ahyP[t] = (g >= 0 && g <  NXr - 1) ? expf(-sig_hy[g] * dh_fac) : 0.0f;
    }
}

// ---------------------------------------------------------------------------
// Seed: steps 0..31 in one dispatch, ONE 1024-thread block (16 waves).
// 32x32 threads x 2x2 cells = 64x64 tile centered on the source. State
// starts exactly zero -> no global loads, no redundancy. Ring reads return
// 0 = true field (support radius <= 31 stays strictly inside the tile).
// Same packed v2f step body as phase_kernel. Writes step-32 state to set A.
// ---------------------------------------------------------------------------
__global__ __launch_bounds__(1024)
void seed_kernel(PParams p)
{
    __shared__ __align__(16) float sE[2][SROWS][SPITCH2];

    const int tid = threadIdx.x;
    const int tj = tid & 31, ti = tid >> 5;
    const int li0 = 2 * ti, lj0 = 2 * tj;
    const int r0 = SB + li0, c0 = SB + lj0;   // padded coords

    const float ca = p.Caa[0], cb = p.Cba[0], cc = p.Cca[0];
    const float cd = p.Cda[0], ce = p.Cea[0];
    const float ca1f = ca + 1.0f;
    const float C1f = p.C1a[0], C2f = p.C2a[0];
    const float cbdxf = p.Cbdxa[0], cbdyf = p.Cbdya[0];
    const float dbhx0 = p.dbhxa[0], dbhy0 = p.dbhya[0];

    const v2f vca1 = mk2(ca1f, ca1f), vcb = mk2(cb, cb), vcc = mk2(cc, cc);
    const v2f vcd = mk2(cd, cd), vce = mk2(ce, ce);
    const v2f vC1 = mk2(C1f, C1f), vC2 = mk2(C2f, C2f);
    const v2f vbx = mk2(cbdxf, cbdxf), vby = mk2(cbdyf, cbdyf);
    const v2f vhx = mk2(dbhx0, dbhx0), vhy = mk2(dbhy0, dbhy0);

    v2f dHx[2], dHy[2], dE[2], dHyU, srcw[2];
    float dHxL[2];
#pragma unroll
    for (int a = 0; a < 2; ++a) {
        float aex = p.aexP[r0 + a], ahxv = p.ahxP[r0 + a], dex = p.dexP[r0 + a];
        dHx[a] = mk2(aex * p.ahyP[c0], aex * p.ahyP[c0 + 1]);
        dHy[a] = mk2(ahxv * p.aeyP[c0], ahxv * p.aeyP[c0 + 1]);
        dE[a]  = mk2(dex * p.deyP[c0], dex * p.deyP[c0 + 1]);
        srcw[a] = mk2(((r0 + a == CP) && (c0 == CP)) ? 1.0f : 0.0f,
                      ((r0 + a == CP) && (c0 + 1 == CP)) ? 1.0f : 0.0f);
    }
    {
        float ahxU = p.ahxP[r0 - 1];          // r0-1 >= SB-1 = 185 >= 0
        float ahyL = p.ahyP[c0 - 1];
        dHyU = mk2(ahxU * p.aeyP[c0], ahxU * p.aeyP[c0 + 1]);
        dHxL[0] = p.aexP[r0] * ahyL;
        dHxL[1] = p.aexP[r0 + 1] * ahyL;
    }

    // Zero state (exact at t=0) -- no global loads at all.
    v2f ez[2] = {}, jz[2] = {}, uu[2] = {}, hx[2] = {}, hy[2] = {};
    v2f hyU = {};
    float hxL[2] = {};

    // Ring-only zero (publishes never touch the ring) -> no barrier needed;
    // the step-0 in-loop barrier orders these writes vs all readers.
    for (int z = tid; z < 2 * RING_N2; z += 1024) {
        int b = (z >= RING_N2) ? 1 : 0;
        int r = b ? z - RING_N2 : z;
        int row, col;
        if (r < 2 * SPITCH2) { row = (r < SPITCH2) ? 0 : (SROWS - 1); col = r % SPITCH2; }
        else { int rr = r - 2 * SPITCH2; row = 1 + (rr >> 2); int c = rr & 3;
               col = (c < 2) ? c : c + 64; }
        sE[b][row][col] = 0.0f;
    }

    // Preload all 32 source values (wave-uniform -> SGPRs)
    float svl[SEED_STEPS];
#pragma unroll
    for (int s = 0; s < SEED_STEPS; ++s) svl[s] = p.src[s];

    for (int s = 0; s < SEED_STEPS; ++s) {
        float (*S)[SPITCH2] = sE[s & 1];
        *(float2*)&S[1 + li0][2 + lj0] = make_float2(ez[0].x, ez[0].y);
        *(float2*)&S[2 + li0][2 + lj0] = make_float2(ez[1].x, ez[1].y);

        // ---- pre-barrier (no neighbor deps) ----
        hy[0] = dHy[0] * (hy[0] + vhy * (ez[1] - ez[0]));
        v2f w0 = hx[0] + vhx * ez[0];
        v2f w1 = hx[1] + vhx * ez[1];

        v2f phi0 = vca1 * jz[0] + vcd * ez[0] + uu[0];
        v2f phi1 = vca1 * jz[1] + vcd * ez[1] + uu[1];
        v2f base0 = vC1 * ez[0] - vC2 * phi0;
        v2f base1 = vC1 * ez[1] - vC2 * phi1;
        v2f pj0 = phi0 - jz[0];
        v2f pj1 = phi1 - jz[1];
        uu[0] = vcb * jz[0] + vce * ez[0];
        uu[1] = vcb * jz[1] + vce * ez[1];

        __syncthreads();

        float eR0 = S[1 + li0][4 + lj0];
        float eR1 = S[2 + li0][4 + lj0];
        float2 eDf = *(float2*)&S[3 + li0][2 + lj0];
        float2 eUf = *(float2*)&S[li0][2 + lj0];
        float eL0 = S[1 + li0][1 + lj0];
        float eL1 = S[2 + li0][1 + lj0];
        v2f eD = mk2(eDf.x, eDf.y), eU = mk2(eUf.x, eUf.y);

        v2f sh0 = mk2(ez[0].y, eR0);
        v2f sh1 = mk2(ez[1].y, eR1);
        hx[0] = dHx[0] * (w0 - vhx * sh0);
        hx[1] = dHx[1] * (w1 - vhx * sh1);
        hy[1] = dHy[1] * (hy[1] + vhy * (eD - ez[1]));

        hyU = dHyU * (hyU + vhy * (ez[0] - eU));
        hxL[0] = dHxL[0] * (hxL[0] - dbhx0 * (ez[0].x - eL0));
        hxL[1] = dHxL[1] * (hxL[1] - dbhx0 * (ez[1].x - eL1));

        v2f cHy0 = hy[0] - hyU;
        v2f cHy1 = hy[1] - hy[0];
        v2f cHx0 = hx[0] - mk2(hxL[0], hx[0].x);
        v2f cHx1 = hx[1] - mk2(hxL[1], hx[1].x);

        float sv = svl[s];
        v2f vsv = mk2(sv, sv);
        v2f en0 = dE[0] * (base0 + vbx * cHy0 - vby * cHx0) + srcw[0] * vsv;
        v2f en1 = dE[1] * (base1 + vbx * cHy1 - vby * cHx1) + srcw[1] * vsv;
        jz[0] = pj0 + vcc * en0;
        jz[1] = pj1 + vcc * en1;
        ez[0] = en0;
        ez[1] = en1;
    }

    // Write step-32 state to set A (phase t=4 is even -> reads A).
#pragma unroll
    for (int a = 0; a < 2; ++a) {
        int g = (r0 + a) * PP + c0;
        *(float2*)&p.aEz[g] = make_float2(ez[a].x, ez[a].y);
        *(float2*)&p.aJz[g] = make_float2(jz[a].x, jz[a].y);
        *(float2*)&p.aU[g]  = make_float2(uu[a].x, uu[a].y);
        *(float2*)&p.aHx[g] = make_float2(hx[a].x, hx[a].y);
        *(float2*)&p.aHy[g] = make_float2(hy[a].x, hy[a].y);
    }
}

// ---------------------------------------------------------------------------
// One temporal-blocked phase (Kt=8 steps), ONE barrier per step.
// Ez is the only field exchanged through LDS (parity-double-buffered tile:
// step s+1 stores to the other buffer, so the single barrier is WAR-safe).
// Ring-only zero (no pre-loop barrier; step-0 barrier orders it vs readers).
// Pre-barrier: publish Ez, hy[0], hx-partial w, Lorentz terms phi/base/pj/u'.
// Post-barrier: 6 LDS reads -> remaining H, ghost H, curls, packed E/J.
// Source FMA gated block-uniformly (only the block containing (CP,CP)).
// writeOut: last phase writes its owned Ez directly to the dense output.
// ---------------------------------------------------------------------------
__global__ __launch_bounds__(256)
void phase_kernel(PParams p, int t, int b0, float* __restrict__ out,
                  int writeOut)
{
    __shared__ __align__(16) float sEz[2][LROWS][SPITCH];

    const int tid = threadIdx.x;
    const int tj = tid & 15, ti = tid >> 4;
    const int li0 = 2 * ti, lj0 = 2 * tj;

    // Bijective XCD-chunked swizzle (grid is always square). Pure permutation.
    const int gx = (int)gridDim.x;
    int orig = (int)blockIdx.y * gx + (int)blockIdx.x;
    int nwg = gx * gx;
    int q = nwg >> 3, rr = nwg & 7;
    int xcd = orig & 7, kk = orig >> 3;
    int nid = (xcd < rr ? xcd * (q + 1) : rr * (q + 1) + (xcd - rr) * q) + kk;
    int bx = nid % gx, by = nid / gx;

    const int r0 = (bx + b0) * Bt + li0;  // padded row, cell(0,*)
    const int c0 = (by + b0) * Bt + lj0;  // padded col, cell(*,0)

    // Block-uniform: does this block's 32x32 extent contain the source cell?
    const int rb = (bx + b0) * Bt, cb2 = (by + b0) * Bt;
    const bool hasSrc = (CP >= rb && CP < rb + EXT && CP >= cb2 && CP < cb2 + EXT);

    const float ca = p.Caa[0], cb = p.Cba[0], cc = p.Cca[0];
    const float cd = p.Cda[0], ce = p.Cea[0];
    const float ca1f = ca + 1.0f;
    const float C1f = p.C1a[0], C2f = p.C2a[0];
    const float cbdxf = p.Cbdxa[0], cbdyf = p.Cbdya[0];
    const float dbhx0 = p.dbhxa[0], dbhy0 = p.dbhya[0];

    const v2f vca1 = mk2(ca1f, ca1f), vcb = mk2(cb, cb), vcc = mk2(cc, cc);
    const v2f vcd = mk2(cd, cd), vce = mk2(ce, ce);
    const v2f vC1 = mk2(C1f, C1f), vC2 = mk2(C2f, C2f);
    const v2f vbx = mk2(cbdxf, cbdxf), vby = mk2(cbdyf, cbdyf);
    const v2f vhx = mk2(dbhx0, dbhx0), vhy = mk2(dbhy0, dbhy0);

    v2f dHx[2], dHy[2], dE[2], dHyU, srcw[2];
    float dHxL[2];
#pragma unroll
    for (int a = 0; a < 2; ++a) {
        float aex = p.aexP[r0 + a], ahxv = p.ahxP[r0 + a], dex = p.dexP[r0 + a];
        dHx[a] = mk2(aex * p.ahyP[c0], aex * p.ahyP[c0 + 1]);
        dHy[a] = mk2(ahxv * p.aeyP[c0], ahxv * p.aeyP[c0 + 1]);
        dE[a]  = mk2(dex * p.deyP[c0], dex * p.deyP[c0 + 1]);
        srcw[a] = mk2(((r0 + a == CP) && (c0 == CP)) ? 1.0f : 0.0f,
                      ((r0 + a == CP) && (c0 + 1 == CP)) ? 1.0f : 0.0f);
    }
    {
        float ahxU = (r0 > 0) ? p.ahxP[r0 - 1] : 0.0f;   // table idx guard
        float ahyL = (c0 > 0) ? p.ahyP[c0 - 1] : 0.0f;
        dHyU = mk2(ahxU * p.aeyP[c0], ahxU * p.aeyP[c0 + 1]);
        dHxL[0] = p.aexP[r0] * ahyL;
        dHxL[1] = p.aexP[r0 + 1] * ahyL;
    }

    const bool odd = (t & 1) != 0;
    const float* cEz = odd ? p.bEz : p.aEz;
    const float* cJz = odd ? p.bJz : p.aJz;
    const float* cU  = odd ? p.bU  : p.aU;
    const float* cHx = odd ? p.bHx : p.aHx;
    const float* cHy = odd ? p.bHy : p.aHy;
    float* nEz = odd ? p.aEz : p.bEz;
    float* nJz = odd ? p.aJz : p.bJz;
    float* nU  = odd ? p.aU  : p.bU;
    float* nHx = odd ? p.aHx : p.bHx;
    float* nHy = odd ? p.aHy : p.bHy;

    // Ring-only zero (publishes never touch the ring) -> no barrier needed;
    // the step-0 in-loop barrier orders these writes vs all readers.
    for (int z = tid; z < 2 * RING_N; z += 256) {
        int b = (z >= RING_N) ? 1 : 0;
        int r = b ? z - RING_N : z;
        int row, col;
        if (r < 2 * SPITCH) { row = (r < SPITCH) ? 0 : (LROWS - 1); col = r % SPITCH; }
        else { int rr2 = r - 2 * SPITCH; row = 1 + (rr2 >> 2); int c = rr2 & 3;
               col = (c < 2) ? c : c + EXT; }
        sEz[b][row][col] = 0.0f;
    }

    // Load 2x2 register state (unconditional padded float2) as packed rows
    v2f ez[2], jz[2], uu[2], hx[2], hy[2];
#pragma unroll
    for (int a = 0; a < 2; ++a) {
        int g = (r0 + a) * PP + c0;
        float2 v;
        v = *(const float2*)&cEz[g]; ez[a] = mk2(v.x, v.y);
        v = *(const float2*)&cJz[g]; jz[a] = mk2(v.x, v.y);
        v = *(const float2*)&cU[g];  uu[a] = mk2(v.x, v.y);
        v = *(const float2*)&cHx[g]; hx[a] = mk2(v.x, v.y);
        v = *(const float2*)&cHy[g]; hy[a] = mk2(v.x, v.y);
    }
    // Ghost H (row above / col left); guard row + zero pads make -1 safe
    v2f hyU;
    float hxL[2];
    {
        float2 v = *(const float2*)&cHy[(r0 - 1) * PP + c0];
        hyU = mk2(v.x, v.y);
        hxL[0] = cHx[r0 * PP + c0 - 1];
        hxL[1] = cHx[(r0 + 1) * PP + c0 - 1];
    }

    // Preload the phase's Kt source values (wave-uniform -> SGPR scalar loads)
    const int n0 = t * Kt;
    float svl[Kt];
#pragma unroll
    for (int s = 0; s < Kt; ++s) svl[s] = p.src[n0 + s];

    for (int s = 0; s < Kt; ++s) {
        float (*S)[SPITCH] = sEz[s & 1];
        // publish all 4 Ez cells into the ring-padded interior
        *(float2*)&S[1 + li0][2 + lj0] = make_float2(ez[0].x, ez[0].y);
        *(float2*)&S[2 + li0][2 + lj0] = make_float2(ez[1].x, ez[1].y);

        // ---- pre-barrier (no neighbor deps) ----
        hy[0] = dHy[0] * (hy[0] + vhy * (ez[1] - ez[0]));
        v2f w0 = hx[0] + vhx * ez[0];          // hx partial: dHx*(w - vhx*sh)
        v2f w1 = hx[1] + vhx * ez[1];

        v2f phi0 = vca1 * jz[0] + vcd * ez[0] + uu[0];
        v2f phi1 = vca1 * jz[1] + vcd * ez[1] + uu[1];
        v2f base0 = vC1 * ez[0] - vC2 * phi0;
        v2f base1 = vC1 * ez[1] - vC2 * phi1;
        v2f pj0 = phi0 - jz[0];
        v2f pj1 = phi1 - jz[1];
        uu[0] = vcb * jz[0] + vce * ez[0];     // u' for the next step
        uu[1] = vcb * jz[1] + vce * ez[1];

        __syncthreads();

        // Unconditional neighbor reads; tile-edge reads hit the zero ring.
        float eR0 = S[1 + li0][4 + lj0];
        float eR1 = S[2 + li0][4 + lj0];
        float2 eDf = *(float2*)&S[3 + li0][2 + lj0];
        float2 eUf = *(float2*)&S[li0][2 + lj0];
        float eL0 = S[1 + li0][1 + lj0];
        float eL1 = S[2 + li0][1 + lj0];
        v2f eD = mk2(eDf.x, eDf.y), eU = mk2(eUf.x, eUf.y);

        // ---- H updates (packed rows; hx needs the column-shifted ez) ----
        v2f sh0 = mk2(ez[0].y, eR0);
        v2f sh1 = mk2(ez[1].y, eR1);
        hx[0] = dHx[0] * (w0 - vhx * sh0);
        hx[1] = dHx[1] * (w1 - vhx * sh1);
        hy[1] = dHy[1] * (hy[1] + vhy * (eD - ez[1]));

        // ---- ghost H update (same arithmetic as the neighbor's own) ----
        hyU = dHyU * (hyU + vhy * (ez[0] - eU));
        hxL[0] = dHxL[0] * (hxL[0] - dbhx0 * (ez[0].x - eL0));
        hxL[1] = dHxL[1] * (hxL[1] - dbhx0 * (ez[1].x - eL1));

        // ---- curls (packed) ----
        v2f cHy0 = hy[0] - hyU;
        v2f cHy1 = hy[1] - hy[0];
        v2f cHx0 = hx[0] - mk2(hxL[0], hx[0].x);
        v2f cHx1 = hx[1] - mk2(hxL[1], hx[1].x);

        // ---- E/J update (packed short chain; src only in the source block) --
        v2f en0 = dE[0] * (base0 + vbx * cHy0 - vby * cHx0);
        v2f en1 = dE[1] * (base1 + vbx * cHy1 - vby * cHx1);
        if (hasSrc) {                          // block-uniform branch
            float sv = svl[s];
            v2f vsv = mk2(sv, sv);
            en0 = en0 + srcw[0] * vsv;
            en1 = en1 + srcw[1] * vsv;
        }
        jz[0] = pj0 + vcc * en0;
        jz[1] = pj1 + vcc * en1;
        ez[0] = en0;
        ez[1] = en1;
        // Single barrier per step: next iteration stores to the OTHER LDS
        // buffer (parity), so late readers of this buffer are safe.
    }

    // store owned interior [Kt, Kt+Bt)^2 -> ti,tj in [4,12)
    if (ti >= 4 && ti < 12 && tj >= 4 && tj < 12) {
#pragma unroll
        for (int a = 0; a < 2; ++a) {
            int g = (r0 + a) * PP + c0;
            *(float2*)&nEz[g] = make_float2(ez[a].x, ez[a].y);
            *(float2*)&nJz[g] = make_float2(jz[a].x, jz[a].y);
            *(float2*)&nU[g]  = make_float2(uu[a].x, uu[a].y);
            *(float2*)&nHx[g] = make_float2(hx[a].x, hx[a].y);
            *(float2*)&nHy[g] = make_float2(hy[a].x, hy[a].y);
        }
        // Last phase: owned regions tile the padded domain exactly; emit the
        // dense 421x421 output directly (same register values copy_out read).
        if (writeOut) {
#pragma unroll
            for (int a = 0; a < 2; ++a) {
                int gi = r0 + a - PAD;
                if (gi < NXr) {
                    int gj = c0 - PAD;
                    if (gj < NXr)     out[gi * NXr + gj]     = ez[a].x;
                    if (gj + 1 < NXr) out[gi * NXr + gj + 1] = ez[a].y;
                }
            }
        }
    }
}

// ---------------------------------------------------------------------------
extern "C" void kernel_launch(void* const* d_in, const int* in_sizes, int n_in,
                              void* d_out, int out_size, void* d_ws, size_t ws_size,
                              hipStream_t stream)
{
    const float* src    = (const float*)d_in[0];
    const float* C1     = (const float*)d_in[1];
    const float* C2     = (const float*)d_in[2];
    const float* Cb_dx  = (const float*)d_in[3];
    const float* Cb_dy  = (const float*)d_in[4];
    const float* dbhx   = (const float*)d_in[5];
    const float* dbhy   = (const float*)d_in[6];
    const float* Ca     = (const float*)d_in[7];
    const float* Cb     = (const float*)d_in[8];
    const float* Cc     = (const float*)d_in[9];
    const float* Cd     = (const float*)d_in[10];
    const float* Ce     = (const float*)d_in[11];
    const float* sig_ex = (const float*)d_in[12];
    const float* sig_ey = (const float*)d_in[13];
    const float* sig_hx = (const float*)d_in[14];
    const float* sig_hy = (const float*)d_in[15];
    // d_in[16] = n_steps (always 200) — hard-coded for graph capture.

    const double EPS0 = 1e-9 / 36.0 / M_PI;
    const double MU0  = 4.0 * M_PI * 1e-7;
    const double C0   = 1.0 / sqrt(MU0 * EPS0);
    const double DXd  = 2.5e-8, DYd = 2.5e-8;
    const double DT   = 0.99 / C0 / sqrt(1.0 / (DXd * DXd) + 1.0 / (DYd * DYd));
    const float de_fac = (float)(DT / EPS0);
    const float dh_fac = (float)(DT / MU0);

    // Workspace: [guard row PP] [10 padded fields] [6 padded tables] (~8 MB)
    float* base = (float*)d_ws;
    float* fields = base + PP;
    float* w = fields + 10 * (size_t)FSZ;
    float* dexP = w; w += PP;
    float* deyP = w; w += PP;
    float* aexP = w; w += PP;
    float* aeyP = w; w += PP;
    float* ahxP = w; w += PP;
    float* ahyP = w; w += PP;

    PParams p;
    p.aEz = fields + 0 * (size_t)FSZ;  p.aJz = fields + 1 * (size_t)FSZ;
    p.aU  = fields + 2 * (size_t)FSZ;  p.aHx = fields + 3 * (size_t)FSZ;
    p.aHy = fields + 4 * (size_t)FSZ;
    p.bEz = fields + 5 * (size_t)FSZ;  p.bJz = fields + 6 * (size_t)FSZ;
    p.bU  = fields + 7 * (size_t)FSZ;  p.bHx = fields + 8 * (size_t)FSZ;
    p.bHy = fields + 9 * (size_t)FSZ;
    p.dexP = dexP; p.deyP = deyP; p.aexP = aexP; p.aeyP = aeyP;
    p.ahxP = ahxP; p.ahyP = ahyP;
    p.C1a = C1; p.C2a = C2; p.Cbdxa = Cb_dx; p.Cbdya = Cb_dy;
    p.Caa = Ca; p.Cba = Cb; p.Cca = Cc; p.Cda = Cd; p.Cea = Ce;
    p.dbhxa = dbhx; p.dbhya = dbhy;
    p.src = src;

    init_kernel<<<512, 256, 0, stream>>>(sig_ex, sig_ey, sig_hx, sig_hy,
                                         de_fac, dh_fac,
                                         base, PP + 10 * FSZ,
                                         dexP, deyP, aexP, aeyP, ahxP, ahyP);

    // Steps 0..31 in one zero-redundancy 1024-thread dispatch. Writes set A.
    seed_kernel<<<1, 1024, 0, stream>>>(p);

    dim3 blk(256);
    for (int t = 4; t < NPHASE; ++t) {
        // Support bound: after n steps the field is confined to a Chebyshev
        // ball of radius n-1 around the source. End of phase t is step 8(t+1)
        // -> radius 8t+7. Tile-extent gate with R = 8t+9: an unlaunched tile
        // has extent disjoint from B(8t+9) => its owned region is disjoint
        // from B(8t+7) = support => true field there is 0 = its stale
        // init-zero. Launch sets monotone in t -> ping-pong skip stays exact.
        // t-only formula -> identical grids every call (capture-safe).
        int R  = 8 * t + 9;
        int lo = CP - R, hi = CP + R;
        int b0 = (lo - (EXT - 1)) / 16; if (b0 < 0) b0 = 0;
        int b1 = hi / 16;               if (b1 > NBLK - 1) b1 = NBLK - 1;
        dim3 g(b1 - b0 + 1, b1 - b0 + 1);
        phase_kernel<<<g, blk, 0, stream>>>(p, t, b0, (float*)d_out,
                                            (t == NPHASE - 1) ? 1 : 0);
    }
    // No copy_out dispatch: phase t=24 wrote the dense output directly.
}